// Round 9
// baseline (153.447 us; speedup 1.0000x reference)
//
#include <hip/hip_runtime.h>
#include <hip/hip_bf16.h>

#define B_ 16
#define T_ 1024
#define MEL_ 80
#define C_ 512
#define NL_ 6
#define NS_ 32
#define HBSTR 1096   // per-wave LDS h-buffer stride (halves): 32 pad + 1024 + 40 tail

typedef _Float16 f16x8 __attribute__((ext_vector_type(8)));
typedef float f32x4 __attribute__((ext_vector_type(4)));

// ---------------------------------------------------------------- wave reduce
__device__ __forceinline__ float wred(float v) {
#pragma unroll
    for (int m = 32; m >= 1; m >>= 1) v += __shfl_xor(v, m, 64);
    return v;
}

__device__ __forceinline__ unsigned int pkh(float a, float b) {
    typedef __fp16 h2 __attribute__((ext_vector_type(2)));
    h2 r = __builtin_amdgcn_cvt_pkrtz(a, b);   // builtin returns __fp16x2
    return __builtin_bit_cast(unsigned int, r);
}
__device__ __forceinline__ float h2f(unsigned short u) {
    return (float)__builtin_bit_cast(_Float16, u);
}

// ---------------------------------------------------------------- tap fragments (self-contained)
// Phase 1: compute taps Kt[(l,c)][tau] = sum_n Cp exp(-exp(logA) tau) (+D at tau=0)
//          into LDS (per-block slice; Kt never touches global).
// Phase 2: build per-(l,c) MFMA A-operand fragments (f16):
//   A_hi[m][k] = K[32+m-k], A_lo[m][k] = K[m-k], zero out of [0,32).
// Fragment layout (v_mfma_f32_16x16x32_f16 A): lane holds A[lane&15][8*(lane>>4)+e].
__global__ __launch_bounds__(256) void tap_frags(const float* __restrict__ logA,
                                                 const float* __restrict__ Cp,
                                                 const float* __restrict__ Dp,
                                                 unsigned short* __restrict__ AH,
                                                 unsigned short* __restrict__ AL) {
    __shared__ float KT[4][32];
    const int gid0 = blockIdx.x * 4;            // gid = l*C + c
    const int tid = threadIdx.x;
    if (tid < 128) {
        int gl = tid >> 5, tau = tid & 31;
        int gid = gid0 + gl;
        const float* la = logA + (size_t)gid * NS_;
        const float* cp = Cp + (size_t)gid * NS_;
        float s = 0.f;
        float t = (float)tau;
#pragma unroll 8
        for (int n = 0; n < NS_; ++n)
            s += cp[n] * expf(-expf(la[n]) * t);
        if (tau == 0) s += Dp[gid];
        KT[gl][tau] = s;
    }
    __syncthreads();
    const int wv = tid >> 6, lane = tid & 63;
    const int gid = gid0 + wv;
    float kv = KT[wv][lane & 31];               // lanes 0..31 hold taps 0..31
    const int m = lane & 15, hh = lane >> 4;
    f16x8 vh, vl;
#pragma unroll
    for (int e = 0; e < 8; ++e) {
        int th = 32 + m - 8 * hh - e;
        int tl = m - 8 * hh - e;
        float a = __shfl(kv, th & 31, 64);
        float bq = __shfl(kv, tl & 31, 64);
        vh[e] = (th >= 0 && th < 32) ? (_Float16)a : (_Float16)0.f;
        vl[e] = (tl >= 0 && tl < 32) ? (_Float16)bq : (_Float16)0.f;
    }
    *(f16x8*)(AH + (size_t)gid * 512 + lane * 8) = vh;
    *(f16x8*)(AL + (size_t)gid * 512 + lane * 8) = vl;
}

// ---------------------------------------------------------------- fused in_proj + 6-layer S4D stack
// R8 lesson: intermediates are L3-resident, so byte-halving is not a lever --
// eliminating whole round trips is. in_proj (mel@w_in GEMM) is fused here as an
// MFMA entry phase; h0T workspace and its kernel are GONE.
//
// Entry GEMM (per block: M=1024 t x N=8 ch x K=80):
//   D[t][c] = sum_k mel[t][k] w_in[k][c];  A-frag = mel rows (lane m=t), B-frag
//   = w_in cols (lane n=c, cols 8..15 zeroed), K = 2 full 32-chunks + chunk2
//   zero-padded on BOTH sides for hh>=2 (avoids OOB past K=80). D col=lane&15,
//   row=4hh+r (R7-verified mappings). + bias + freq, pack f16 -> HB (cross-wave
//   writes, one barrier).
// Layer loop (R7-proven): ONE CHANNEL PER WAVE, wave-private hb; per layer:
//   8 ds_read_b128, 8 mfma_f32_16x16x32_f16 (Toeplitz hi/lo split), gelu, pack.
__global__ __launch_bounds__(512) void conv_stack(const float* __restrict__ mel,
                                                  const float* __restrict__ w_in,
                                                  const float* __restrict__ b_in,
                                                  const float* __restrict__ freq,
                                                  const unsigned short* __restrict__ AH,
                                                  const unsigned short* __restrict__ AL,
                                                  unsigned short* __restrict__ hfin,
                                                  float* __restrict__ hm) {
    __shared__ unsigned short HB[8 * HBSTR];   // 17,536 B
    const int b = blockIdx.y;
    const int gx = blockIdx.x;                       // 64 groups
    const int c0 = 8 * (((gx & 7) << 3) | (gx >> 3)); // XCD i -> channels 64i..64i+63
    const int tid = threadIdx.x;
    const int lane = tid & 63;
    const int wv = tid >> 6;
    const int c = __builtin_amdgcn_readfirstlane(c0 + wv);   // wave-uniform channel
    unsigned short* hb = &HB[wv * HBSTR];
    const int n = lane & 15, hh = lane >> 4;

    // zero pads: [0,32) front (h[t<0]=0), [1056,1096) tail (avoid NaN*0 in MFMA)
    if (lane < 32) hb[lane] = 0;
    if (lane < 40) hb[1056 + lane] = 0;

    {   // ---- entry GEMM: h0 = mel @ w_in + bias + freq, straight into HB ----
        f16x8 Wf[3];
#pragma unroll
        for (int ch = 0; ch < 3; ++ch) {
            f16x8 w;
#pragma unroll
            for (int e = 0; e < 8; ++e) {
                int k = 32 * ch + 8 * hh + e;
                float v = (n < 8 && k < MEL_) ? w_in[(size_t)k * C_ + c0 + n] : 0.f;
                w[e] = (_Float16)v;
            }
            Wf[ch] = w;
        }
        float biasn = (n < 8) ? b_in[c0 + n] : 0.f;
        const float* melb = mel + (size_t)b * T_ * MEL_;
#pragma unroll
        for (int tt = 0; tt < 8; ++tt) {
            const int tbase = 128 * wv + 16 * tt;
            f16x8 Am[3];
#pragma unroll
            for (int ch = 0; ch < 3; ++ch) {
                f16x8 a = {0, 0, 0, 0, 0, 0, 0, 0};
                if (ch < 2 || hh < 2) {
                    const float* mp = melb + (size_t)(tbase + n) * MEL_ + 32 * ch + 8 * hh;
                    float4 m0 = *(const float4*)(mp);
                    float4 m1 = *(const float4*)(mp + 4);
                    a[0] = (_Float16)m0.x; a[1] = (_Float16)m0.y;
                    a[2] = (_Float16)m0.z; a[3] = (_Float16)m0.w;
                    a[4] = (_Float16)m1.x; a[5] = (_Float16)m1.y;
                    a[6] = (_Float16)m1.z; a[7] = (_Float16)m1.w;
                }
                Am[ch] = a;
            }
            f32x4 d = {0.f, 0.f, 0.f, 0.f};
            d = __builtin_amdgcn_mfma_f32_16x16x32_f16(Am[0], Wf[0], d, 0, 0, 0);
            d = __builtin_amdgcn_mfma_f32_16x16x32_f16(Am[1], Wf[1], d, 0, 0, 0);
            d = __builtin_amdgcn_mfma_f32_16x16x32_f16(Am[2], Wf[2], d, 0, 0, 0);
            if (n < 8) {
                float v[4];
#pragma unroll
                for (int r = 0; r < 4; ++r) {
                    int t = tbase + 4 * hh + r;
                    int fr = t < 513 ? t : 512;
                    v[r] = d[r] + biasn + freq[(size_t)fr * C_ + c0 + n];
                }
                uint2 pw;
                pw.x = pkh(v[0], v[1]);
                pw.y = pkh(v[2], v[3]);
                *(uint2*)(&HB[n * HBSTR + 32 + tbase + 4 * hh]) = pw;
            }
        }
    }
    __syncthreads();

    const int boff = 16 * n + 8 * hh;                // q-base added in loop
    const int woff = 32 + 16 * n + 4 * hh;           // layer output write base

    f16x8 Ah = *(const f16x8*)(AH + (size_t)c * 512 + lane * 8);   // l=0
    f16x8 Al = *(const f16x8*)(AL + (size_t)c * 512 + lane * 8);

    float hsum = 0.f;
    for (int l = 0; l < NL_; ++l) {
        const int ln = (l + 1 < NL_) ? l + 1 : 0;    // dummy prefetch on last
        f16x8 nAh = *(const f16x8*)(AH + ((size_t)ln * C_ + c) * 512 + lane * 8);
        f16x8 nAl = *(const f16x8*)(AL + ((size_t)ln * C_ + c) * 512 + lane * 8);

        f32x4 d[4];
#pragma unroll
        for (int q = 0; q < 4; ++q) {
            const unsigned short* base = hb + 256 * q + boff;
            f16x8 Bh = *(const f16x8*)(base);          // h[256q+16n-32+k]
            f16x8 Bl = *(const f16x8*)(base + 32);     // h[256q+16n+k]
            f32x4 z = {0.f, 0.f, 0.f, 0.f};
            d[q] = __builtin_amdgcn_mfma_f32_16x16x32_f16(Ah, Bh, z, 0, 0, 0);
            d[q] = __builtin_amdgcn_mfma_f32_16x16x32_f16(Al, Bl, d[q], 0, 0, 0);
        }
        // gelu (f32) + pack back to f16 h-buffer
#pragma unroll
        for (int q = 0; q < 4; ++q) {
            float g[4];
#pragma unroll
            for (int r = 0; r < 4; ++r) {
                float y = d[q][r];
                float u2 = y * (y * y * 0.07135481627f + 1.59576912161f);
                float rr = __builtin_amdgcn_rcpf(__expf(u2) + 1.f);
                g[r] = y - y * rr;
            }
            if (l == NL_ - 1) hsum += g[0] + g[1] + g[2] + g[3];
            uint2 pw;
            pw.x = pkh(g[0], g[1]);
            pw.y = pkh(g[2], g[3]);
            *(uint2*)(&hb[woff + 256 * q]) = pw;       // t = 256q+16n+4hh+r
        }
        Ah = nAh; Al = nAl;
    }

    // time mean per channel
    {
        float s = wred(hsum);
        if (lane == 0) hm[(size_t)b * C_ + c] = s * (1.f / T_);
    }

    // exit: cross-wave LDS transpose -> hfin16[b][t][C] (raw u16 copy)
    __syncthreads();
    {
        unsigned short* dst = hfin + (size_t)b * T_ * C_ + c0;
#pragma unroll
        for (int it = 0; it < 4; ++it) {
            int idx = it * 512 + tid;                 // 0..2047
            int t = idx >> 1, u = idx & 1;
            unsigned int w0 = (unsigned int)HB[(4 * u + 0) * HBSTR + 32 + t] |
                              ((unsigned int)HB[(4 * u + 1) * HBSTR + 32 + t] << 16);
            unsigned int w1 = (unsigned int)HB[(4 * u + 2) * HBSTR + 32 + t] |
                              ((unsigned int)HB[(4 * u + 3) * HBSTR + 32 + t] << 16);
            uint2 pw = {w0, w1};
            *(uint2*)(dst + (size_t)t * C_ + 4 * u) = pw;
        }
    }
}

// ---------------------------------------------------------------- per-row heads
// Row-major single-pass version: params hoisted into registers once per wave;
// each wave processes 4 rows. Input h is f16 (widened on load -- exact).
__global__ __launch_bounds__(256) void heads_rows(const unsigned short* __restrict__ h,
                                                  const float* __restrict__ ln_g,
                                                  const float* __restrict__ ln_b,
                                                  const float* __restrict__ w5,
                                                  const float* __restrict__ b5,
                                                  float* __restrict__ out) {
    int wv = threadIdx.x >> 6, lane = threadIdx.x & 63;
    int r0 = blockIdx.x * 16 + wv * 4;
    float g[3][8], bb[3][8], ww[3][8];
#pragma unroll
    for (int o = 0; o < 3; ++o) {
        const float* gp = ln_g + o * C_ + lane * 8;
        const float* bp = ln_b + o * C_ + lane * 8;
        const float* wp = w5 + o * C_ + lane * 8;
        float4 a, bq;
        a = *(const float4*)(gp); bq = *(const float4*)(gp + 4);
        g[o][0]=a.x; g[o][1]=a.y; g[o][2]=a.z; g[o][3]=a.w;
        g[o][4]=bq.x; g[o][5]=bq.y; g[o][6]=bq.z; g[o][7]=bq.w;
        a = *(const float4*)(bp); bq = *(const float4*)(bp + 4);
        bb[o][0]=a.x; bb[o][1]=a.y; bb[o][2]=a.z; bb[o][3]=a.w;
        bb[o][4]=bq.x; bb[o][5]=bq.y; bb[o][6]=bq.z; bb[o][7]=bq.w;
        a = *(const float4*)(wp); bq = *(const float4*)(wp + 4);
        ww[o][0]=a.x; ww[o][1]=a.y; ww[o][2]=a.z; ww[o][3]=a.w;
        ww[o][4]=bq.x; ww[o][5]=bq.y; ww[o][6]=bq.z; ww[o][7]=bq.w;
    }
    float b5r[3] = {b5[0], b5[1], b5[2]};
#pragma unroll
    for (int rr = 0; rr < 4; ++rr) {
        const int r = r0 + rr;
        const unsigned short* row = h + (size_t)r * C_ + lane * 8;
        float x[8];
        {
            uint4 q = *(const uint4*)(row);
            x[0] = h2f((unsigned short)(q.x & 0xffff));
            x[1] = h2f((unsigned short)(q.x >> 16));
            x[2] = h2f((unsigned short)(q.y & 0xffff));
            x[3] = h2f((unsigned short)(q.y >> 16));
            x[4] = h2f((unsigned short)(q.z & 0xffff));
            x[5] = h2f((unsigned short)(q.z >> 16));
            x[6] = h2f((unsigned short)(q.w & 0xffff));
            x[7] = h2f((unsigned short)(q.w >> 16));
        }
        float s = 0.f;
#pragma unroll
        for (int i = 0; i < 8; ++i) s += x[i];
        float mu = wred(s) * (1.f / C_);
        float v = 0.f;
#pragma unroll
        for (int i = 0; i < 8; ++i) { float d = x[i] - mu; v += d * d; }
        float rstd = rsqrtf(wred(v) * (1.f / C_) + 1e-5f);
#pragma unroll
        for (int o = 0; o < 3; ++o) {
            float acc = 0.f;
#pragma unroll
            for (int i = 0; i < 8; ++i) {
                float xn = (x[i] - mu) * rstd * g[o][i] + bb[o][i];
                acc += xn * ww[o][i];
            }
            acc = wred(acc);
            if (lane == 0) out[o * (B_ * T_) + r] = acc + b5r[o];
        }
    }
}

// ---------------------------------------------------------------- utterance heads
__global__ __launch_bounds__(64) void heads_utt(const float* __restrict__ hm,
                                                const float* __restrict__ ln_g,
                                                const float* __restrict__ ln_b,
                                                const float* __restrict__ w5,
                                                const float* __restrict__ b5,
                                                const float* __restrict__ wm,
                                                const float* __restrict__ bm,
                                                float* __restrict__ out) {
    int b = blockIdx.x;
    int lane = threadIdx.x;
    const float* row = hm + (size_t)b * C_;
    float x[8];
#pragma unroll
    for (int i = 0; i < 8; ++i) x[i] = row[lane + 64 * i];
    float s = 0.f;
#pragma unroll
    for (int i = 0; i < 8; ++i) s += x[i];
    float mu = wred(s) * (1.f / C_);
    float v = 0.f;
#pragma unroll
    for (int i = 0; i < 8; ++i) { float d = x[i] - mu; v += d * d; }
    float rstd = rsqrtf(wred(v) * (1.f / C_) + 1e-5f);

    const int OUT_SR = 3 * B_ * T_;              // 49152
    const int OUT_PD = OUT_SR + B_;              // 49168
    const int OUT_MF = OUT_PD + B_;              // 49184
#pragma unroll
    for (int o = 3; o <= 4; ++o) {
        float acc = 0.f;
#pragma unroll
        for (int i = 0; i < 8; ++i) {
            int cc = lane + 64 * i;
            float xn = (x[i] - mu) * rstd * ln_g[o * C_ + cc] + ln_b[o * C_ + cc];
            acc += xn * w5[o * C_ + cc];
        }
        acc = wred(acc);
        if (lane == 0) out[(o == 3 ? OUT_SR : OUT_PD) + b] = acc + b5[o];
    }
    float mf[13];
#pragma unroll
    for (int j = 0; j < 13; ++j) mf[j] = 0.f;
#pragma unroll
    for (int i = 0; i < 8; ++i) {
        int cc = lane + 64 * i;
        float xn = (x[i] - mu) * rstd * ln_g[5 * C_ + cc] + ln_b[5 * C_ + cc];
#pragma unroll
        for (int j = 0; j < 13; ++j) mf[j] += xn * wm[cc * 13 + j];
    }
#pragma unroll
    for (int j = 0; j < 13; ++j) {
        float m = wred(mf[j]);
        if (lane == 0) out[OUT_MF + b * 13 + j] = m + bm[j];
    }
}

// ---------------------------------------------------------------- launch
extern "C" void kernel_launch(void* const* d_in, const int* in_sizes, int n_in,
                              void* d_out, int out_size, void* d_ws, size_t ws_size,
                              hipStream_t stream) {
    const float* mel   = (const float*)d_in[0];
    const float* w_in  = (const float*)d_in[1];
    const float* b_in  = (const float*)d_in[2];
    const float* freq  = (const float*)d_in[3];
    const float* logA  = (const float*)d_in[4];
    const float* s4C   = (const float*)d_in[5];
    const float* s4D   = (const float*)d_in[6];
    const float* ln_g  = (const float*)d_in[7];
    const float* ln_b  = (const float*)d_in[8];
    const float* w5    = (const float*)d_in[9];
    const float* b5    = (const float*)d_in[10];
    const float* wm    = (const float*)d_in[11];
    const float* bm    = (const float*)d_in[12];
    float* out = (float*)d_out;

    char* ws = (char*)d_ws;
    const size_t H16 = (size_t)B_ * T_ * C_ * sizeof(unsigned short);  // 16.78 MB
    unsigned short* hB16 = (unsigned short*)ws;                        // hfin16 [b][t][C]
    float* hm = (float*)(ws + H16);                                    // 16*512 f32
    unsigned short* AH = (unsigned short*)(ws + H16 +
                                           (size_t)B_ * C_ * sizeof(float));
    unsigned short* AL = AH + (size_t)NL_ * C_ * 512;                  // 3.1 MB each

    tap_frags<<<(NL_ * C_) / 4, 256, 0, stream>>>(logA, s4C, s4D, AH, AL);
    conv_stack<<<dim3(C_ / 8, B_), 512, 0, stream>>>(mel, w_in, b_in, freq,
                                                     AH, AL, hB16, hm);
    heads_rows<<<(B_ * T_) / 16, 256, 0, stream>>>(hB16, ln_g, ln_b, w5, b5, out);
    heads_utt<<<B_, 64, 0, stream>>>(hm, ln_g, ln_b, w5, b5, wm, bm, out);
}